// Round 4
// baseline (328.252 us; speedup 1.0000x reference)
//
#include <hip/hip_runtime.h>

#define IMG_W 512
#define IMG_H 512
#define TILE 88      // output tile per block
#define HALO 20      // >= 19 dilation steps of halo
#define NSTEP 19     // dilations accumulated (k=1..19; k=0 term is x itself)
#define RH 8
#define RW 8
#define REG 128      // region = 128x128, threads 16x16, 8x8 px/thread in regs

__device__ __forceinline__ float max3f(float a, float b, float c) {
    return fmaxf(fmaxf(a, b), c);   // -> v_max3_f32
}

// DPP lane shifts within 16-lane rows (tx = lane%16). bound_ctrl=1: lanes with
// no source get 0.0f — lands only in region cols 0/127 (halo, garbage-tolerant)
// and avoids the old-dest tie-copy the bound_ctrl=0 form forces.
__device__ __forceinline__ float dpp_shr1(float v) { // receive from lane-1 (left nbr)
    int i = __builtin_bit_cast(int, v);
    i = __builtin_amdgcn_update_dpp(0, i, 0x111, 0xf, 0xf, true); // row_shr:1
    return __builtin_bit_cast(float, i);
}
__device__ __forceinline__ float dpp_shl1(float v) { // receive from lane+1 (right nbr)
    int i = __builtin_bit_cast(int, v);
    i = __builtin_amdgcn_update_dpp(0, i, 0x101, 0xf, 0xf, true); // row_shl:1
    return __builtin_bit_cast(float, i);
}

// Horizontal 3-max. NO masking: invariant is A==0 at out-of-image cells at the
// start of each step; consumers mask the final dilated value once.
__device__ __forceinline__ void hrow(const float (&Ar)[RW], float (&h)[RW]) {
    float hl = dpp_shr1(Ar[RW - 1]);
    float hr = dpp_shl1(Ar[0]);
    h[0] = max3f(hl, Ar[0], Ar[1]);
    #pragma unroll
    for (int c = 1; c < RW - 1; ++c) h[c] = max3f(Ar[c - 1], Ar[c], Ar[c + 1]);
    h[RW - 1] = max3f(Ar[RW - 2], Ar[RW - 1], hr);
}

// One output row: D = max3(h[r-1], h[r], h[r+1]); mask ONCE on the result;
// store to A (in place) and accumulate.
template<bool XM, bool YM>
__device__ __forceinline__ void rowop(const float (&hm1)[RW], const float (&hc)[RW],
                                      const float (&hn)[RW], float (&Ar)[RW],
                                      float (&accr)[RW], const float (&colm)[RW],
                                      float rm, bool needR) {
    float v[RW];
    #pragma unroll
    for (int c = 0; c < RW; ++c) v[c] = max3f(hm1[c], hc[c], hn[c]);
    if (XM) {
        #pragma unroll
        for (int c = 0; c < RW; ++c) v[c] *= colm[c];
    }
    if (YM) {
        if (needR) {
            #pragma unroll
            for (int c = 0; c < RW; ++c) v[c] *= rm;
        }
    }
    #pragma unroll
    for (int c = 0; c < RW; ++c) { Ar[c] = v[c]; accr[c] += v[c]; }
}

template<bool XM, bool YM>
__device__ __forceinline__ void body(const float* __restrict__ xc, float* __restrict__ oc,
                                     int gx0, int gy0, int tx, int ty,
                                     float4 (*topH4)[2][16][16], float4 (*botH4)[2][16][16]) {
    const int rx = tx * RW;      // chunk origin in region coords
    const int ry = ty * RH;
    const int gx = gx0 + rx;     // chunk origin in global coords
    const int gy = gy0 + ry;

    float A[RH][RW];    // current image
    float acc[RH][RW];  // sum of D_k
    float colm[RW], rowm[RH];
    bool needR = false;

    if (XM) {
        #pragma unroll
        for (int c = 0; c < RW; ++c) {
            int xx = gx + c;
            colm[c] = (xx >= 0 && xx < IMG_W) ? 1.f : 0.f;
        }
    }
    if (YM) {
        #pragma unroll
        for (int r = 0; r < RH; ++r) {
            int yy = gy + r;
            rowm[r] = (yy >= 0 && yy < IMG_H) ? 1.f : 0.f;
        }
        needR = (gy < 0) || (gy + RH > IMG_H);
    }

    if (XM || YM) {
        const bool fullin = (gx >= 0) && (gx + RW <= IMG_W) && (gy >= 0) && (gy + RH <= IMG_H);
        if (fullin) {
            #pragma unroll
            for (int r = 0; r < RH; ++r) {
                const float4* rp = (const float4*)(xc + (size_t)(gy + r) * IMG_W + gx);
                float4 v0 = rp[0], v1 = rp[1];
                A[r][0] = v0.x; A[r][1] = v0.y; A[r][2] = v0.z; A[r][3] = v0.w;
                A[r][4] = v1.x; A[r][5] = v1.y; A[r][6] = v1.z; A[r][7] = v1.w;
            }
        } else {
            #pragma unroll
            for (int r = 0; r < RH; ++r) {
                const int yr = gy + r;
                const int yy = min(max(yr, 0), IMG_H - 1);
                float rmv = (yr >= 0 && yr < IMG_H) ? 1.f : 0.f;
                const float* rp = xc + (size_t)yy * IMG_W;
                #pragma unroll
                for (int c = 0; c < RW; ++c) {
                    const int xr = gx + c;
                    const int xx = min(max(xr, 0), IMG_W - 1);
                    float m = rmv;
                    if (XM) m *= colm[c];
                    A[r][c] = rp[xx] * m;
                }
            }
        }
    } else {
        #pragma unroll
        for (int r = 0; r < RH; ++r) {
            const float4* rp = (const float4*)(xc + (size_t)(gy + r) * IMG_W + gx);
            float4 v0 = rp[0], v1 = rp[1];
            A[r][0] = v0.x; A[r][1] = v0.y; A[r][2] = v0.z; A[r][3] = v0.w;
            A[r][4] = v1.x; A[r][5] = v1.y; A[r][6] = v1.z; A[r][7] = v1.w;
        }
    }
    #pragma unroll
    for (int r = 0; r < RH; ++r) {
        #pragma unroll
        for (int c = 0; c < RW; ++c) acc[r][c] = A[r][c];
    }

    const int tyu = ty > 0  ? ty - 1 : 0;    // clamped: region-edge garbage OK
    const int tyd = ty < 15 ? ty + 1 : 15;

    // --- prologue: exchange boundary h rows for step 0 ---
    float ht[RW], hb[RW];                     // h(A[0]), h(A[7]) for CURRENT step
    hrow(A[0], ht); hrow(A[RH - 1], hb);
    topH4[0][0][ty][tx] = make_float4(ht[0], ht[1], ht[2], ht[3]);
    topH4[0][1][ty][tx] = make_float4(ht[4], ht[5], ht[6], ht[7]);
    botH4[0][0][ty][tx] = make_float4(hb[0], hb[1], hb[2], hb[3]);
    botH4[0][1][ty][tx] = make_float4(hb[4], hb[5], hb[6], hb[7]);
    __syncthreads();
    float4 u0 = botH4[0][0][tyu][tx], u1 = botH4[0][1][tyu][tx];   // h row -1
    float4 d0 = topH4[0][0][tyd][tx], d1 = topH4[0][1][tyd][tx];   // h row +8

    // --- pipelined step loop: one barrier per step, LDS latencies overlapped ---
    #pragma unroll 1
    for (int s = 0; s < NSTEP; ++s) {
        float hm1[RW], hbt[RW];
        hm1[0] = u0.x; hm1[1] = u0.y; hm1[2] = u0.z; hm1[3] = u0.w;
        hm1[4] = u1.x; hm1[5] = u1.y; hm1[6] = u1.z; hm1[7] = u1.w;
        hbt[0] = d0.x; hbt[1] = d0.y; hbt[2] = d0.z; hbt[3] = d0.w;
        hbt[4] = d1.x; hbt[5] = d1.y; hbt[6] = d1.z; hbt[7] = d1.w;

        // Boundary rows FIRST (consume prev-iteration LDS reads early), then
        // write next step's boundary h rows so they drain during interior work.
        float h1[RW]; hrow(A[1], h1);
        rowop<XM, YM>(hm1, ht, h1, A[0], acc[0], colm, YM ? rowm[0] : 1.f, needR);
        float h6[RW]; hrow(A[6], h6);
        rowop<XM, YM>(h6, hb, hbt, A[7], acc[7], colm, YM ? rowm[7] : 1.f, needR);

        const int nbuf = (s & 1) ^ 1;
        const bool more = (s + 1 < NSTEP);
        float htn[RW], hbn[RW];
        if (more) {
            hrow(A[0], htn);             // h of masked D0 (A[0] just updated)
            hrow(A[7], hbn);             // h of masked D7
            topH4[nbuf][0][ty][tx] = make_float4(htn[0], htn[1], htn[2], htn[3]);
            topH4[nbuf][1][ty][tx] = make_float4(htn[4], htn[5], htn[6], htn[7]);
            botH4[nbuf][0][ty][tx] = make_float4(hbn[0], hbn[1], hbn[2], hbn[3]);
            botH4[nbuf][1][ty][tx] = make_float4(hbn[4], hbn[5], hbn[6], hbn[7]);
        }

        // Interior rows 1..6 — ~6 rows of VALU hide the ds_write drain.
        float h2[RW]; hrow(A[2], h2);
        rowop<XM, YM>(ht, h1, h2, A[1], acc[1], colm, YM ? rowm[1] : 1.f, needR);
        float h3[RW]; hrow(A[3], h3);
        rowop<XM, YM>(h1, h2, h3, A[2], acc[2], colm, YM ? rowm[2] : 1.f, needR);
        float h4[RW]; hrow(A[4], h4);
        rowop<XM, YM>(h2, h3, h4, A[3], acc[3], colm, YM ? rowm[3] : 1.f, needR);
        float h5[RW]; hrow(A[5], h5);
        rowop<XM, YM>(h3, h4, h5, A[4], acc[4], colm, YM ? rowm[4] : 1.f, needR);
        rowop<XM, YM>(h4, h5, h6, A[5], acc[5], colm, YM ? rowm[5] : 1.f, needR);
        rowop<XM, YM>(h5, h6, hb, A[6], acc[6], colm, YM ? rowm[6] : 1.f, needR);

        if (more) {
            __syncthreads();             // writes drained during interior rows
            u0 = botH4[nbuf][0][tyu][tx]; u1 = botH4[nbuf][1][tyu][tx];
            d0 = topH4[nbuf][0][tyd][tx]; d1 = topH4[nbuf][1][tyd][tx];
            // reads consumed at next iteration's first rowop (~1 hrow later)
            #pragma unroll
            for (int c = 0; c < RW; ++c) { ht[c] = htn[c]; hb[c] = hbn[c]; }
        }
    }

    // Epilogue: store central TILE x TILE (region coords [HALO, HALO+TILE))
    if (XM || YM) {
        #pragma unroll
        for (int r = 0; r < RH; ++r) {
            const int rr = ry + r;
            const int yy = gy0 + rr;
            if (rr >= HALO && rr < HALO + TILE && yy < IMG_H) {
                #pragma unroll
                for (int c = 0; c < RW; ++c) {
                    const int cc = rx + c;
                    const int xx = gx0 + cc;
                    if (cc >= HALO && cc < HALO + TILE && xx < IMG_W)
                        oc[(size_t)yy * IMG_W + xx] = 0.05f * acc[r][c];
                }
            }
        }
    } else {
        #pragma unroll
        for (int r = 0; r < RH; ++r) {
            const int rr = ry + r;
            if (rr < HALO || rr >= HALO + TILE) continue;
            const int yy = gy0 + rr;
            float* rowp = oc + (size_t)yy * IMG_W + gx;
            if (tx >= 3 && tx <= 12) {
                ((float4*)rowp)[0] = make_float4(0.05f * acc[r][0], 0.05f * acc[r][1],
                                                 0.05f * acc[r][2], 0.05f * acc[r][3]);
                ((float4*)rowp)[1] = make_float4(0.05f * acc[r][4], 0.05f * acc[r][5],
                                                 0.05f * acc[r][6], 0.05f * acc[r][7]);
            } else if (tx == 2) {        // cols 16..23, valid 20..23 -> c=4..7
                ((float4*)rowp)[1] = make_float4(0.05f * acc[r][4], 0.05f * acc[r][5],
                                                 0.05f * acc[r][6], 0.05f * acc[r][7]);
            } else if (tx == 13) {       // cols 104..111, valid 104..107 -> c=0..3
                ((float4*)rowp)[0] = make_float4(0.05f * acc[r][0], 0.05f * acc[r][1],
                                                 0.05f * acc[r][2], 0.05f * acc[r][3]);
            }
        }
    }
}

__global__ __launch_bounds__(256, 2)
void blur_outwards_kernel(const float* __restrict__ x, float* __restrict__ out) {
    __shared__ float4 topH4[2][2][16][16];   // 16 KB
    __shared__ float4 botH4[2][2][16][16];   // 16 KB

    const int tid = threadIdx.x;
    const int tx = tid & 15;
    const int ty = tid >> 4;

    const int ch  = blockIdx.z;                       // 0..95
    const int gx0 = (int)blockIdx.x * TILE - HALO;
    const int gy0 = (int)blockIdx.y * TILE - HALO;

    const float* __restrict__ xc = x + (size_t)ch * (IMG_W * IMG_H);
    float* __restrict__ oc = out + (size_t)ch * (IMG_W * IMG_H);

    const bool xe = (gx0 < 0) || (gx0 + REG > IMG_W);
    const bool ye = (gy0 < 0) || (gy0 + REG > IMG_H);
    if (!xe && !ye)      body<false, false>(xc, oc, gx0, gy0, tx, ty, topH4, botH4);
    else if (xe && !ye)  body<true,  false>(xc, oc, gx0, gy0, tx, ty, topH4, botH4);
    else if (!xe && ye)  body<false, true >(xc, oc, gx0, gy0, tx, ty, topH4, botH4);
    else                 body<true,  true >(xc, oc, gx0, gy0, tx, ty, topH4, botH4);
}

extern "C" void kernel_launch(void* const* d_in, const int* in_sizes, int n_in,
                              void* d_out, int out_size, void* d_ws, size_t ws_size,
                              hipStream_t stream) {
    const float* x = (const float*)d_in[0];
    float* out = (float*)d_out;
    dim3 grid((IMG_W + TILE - 1) / TILE,   // 6
              (IMG_H + TILE - 1) / TILE,   // 6
              96);                          // 32 batch * 3 channels
    blur_outwards_kernel<<<grid, 256, 0, stream>>>(x, out);
}

// Round 6
// 313.856 us; speedup vs baseline: 1.0459x; 1.0459x over previous
//
#include <hip/hip_runtime.h>

#define IMG_W 512
#define IMG_H 512
#define TILE 88      // output tile per block
#define HALO 20      // >= 19 dilation steps of halo
#define NSTEP 19     // dilations accumulated (k=1..19; k=0 term is x itself)
#define RH 8
#define RW 8
#define REG 128      // region = 128x128, threads 16x16, 8x8 px/thread in regs

__device__ __forceinline__ float max3f(float a, float b, float c) {
    return fmaxf(fmaxf(a, b), c);   // -> v_max3_f32
}

// DPP lane shifts within 16-lane rows (tx = lane%16). bound_ctrl=1: lanes with
// no source get 0.0f — lands only in region cols 0/127 (halo, garbage-tolerant).
__device__ __forceinline__ float dpp_shr1(float v) { // receive from lane-1 (left nbr)
    int i = __builtin_bit_cast(int, v);
    i = __builtin_amdgcn_update_dpp(0, i, 0x111, 0xf, 0xf, true); // row_shr:1
    return __builtin_bit_cast(float, i);
}
__device__ __forceinline__ float dpp_shl1(float v) { // receive from lane+1 (right nbr)
    int i = __builtin_bit_cast(int, v);
    i = __builtin_amdgcn_update_dpp(0, i, 0x101, 0xf, 0xf, true); // row_shl:1
    return __builtin_bit_cast(float, i);
}
// Pull value from an arbitrary lane (byte addr = srcLane*4, wraps mod 64).
__device__ __forceinline__ float bperm(int byteAddr, float v) {
    int i = __builtin_amdgcn_ds_bpermute(byteAddr, __builtin_bit_cast(int, v));
    return __builtin_bit_cast(float, i);
}

// Horizontal 3-max. NO masking: invariant is A==0 at out-of-image cells at the
// start of each step; consumers mask the final dilated value once.
__device__ __forceinline__ void hrow(const float (&Ar)[RW], float (&h)[RW]) {
    float hl = dpp_shr1(Ar[RW - 1]);
    float hr = dpp_shl1(Ar[0]);
    h[0] = max3f(hl, Ar[0], Ar[1]);
    #pragma unroll
    for (int c = 1; c < RW - 1; ++c) h[c] = max3f(Ar[c - 1], Ar[c], Ar[c + 1]);
    h[RW - 1] = max3f(Ar[RW - 2], Ar[RW - 1], hr);
}

// One output row: D = max3(h[r-1], h[r], h[r+1]); mask ONCE on the result.
template<bool XM, bool YM>
__device__ __forceinline__ void rowop(const float (&hm1)[RW], const float (&hc)[RW],
                                      const float (&hn)[RW], float (&Ar)[RW],
                                      float (&accr)[RW], const float (&colm)[RW],
                                      float rm, bool needR) {
    float v[RW];
    #pragma unroll
    for (int c = 0; c < RW; ++c) v[c] = max3f(hm1[c], hc[c], hn[c]);
    if (XM) {
        #pragma unroll
        for (int c = 0; c < RW; ++c) v[c] *= colm[c];
    }
    if (YM) {
        if (needR) {
            #pragma unroll
            for (int c = 0; c < RW; ++c) v[c] *= rm;
        }
    }
    #pragma unroll
    for (int c = 0; c < RW; ++c) { Ar[c] = v[c]; accr[c] += v[c]; }
}

template<bool XM, bool YM>
__device__ __forceinline__ void body(const float* __restrict__ xc, float* __restrict__ oc,
                                     int gx0, int gy0, int tx, int ty, int lane,
                                     float4 (*botR)[4][16][2], float4 (*topR)[4][16][2]) {
    const int rx = tx * RW;      // chunk origin in region coords
    const int ry = ty * RH;
    const int gx = gx0 + rx;     // chunk origin in global coords
    const int gy = gy0 + ry;

    float A[RH][RW];    // current image
    float acc[RH][RW];  // sum of D_k
    float colm[RW], rowm[RH];
    bool needR = false;

    if (XM) {
        #pragma unroll
        for (int c = 0; c < RW; ++c) {
            int xx = gx + c;
            colm[c] = (xx >= 0 && xx < IMG_W) ? 1.f : 0.f;
        }
    }
    if (YM) {
        #pragma unroll
        for (int r = 0; r < RH; ++r) {
            int yy = gy + r;
            rowm[r] = (yy >= 0 && yy < IMG_H) ? 1.f : 0.f;
        }
        needR = (gy < 0) || (gy + RH > IMG_H);
    }

    if (XM || YM) {
        const bool fullin = (gx >= 0) && (gx + RW <= IMG_W) && (gy >= 0) && (gy + RH <= IMG_H);
        if (fullin) {
            #pragma unroll
            for (int r = 0; r < RH; ++r) {
                const float4* rp = (const float4*)(xc + (size_t)(gy + r) * IMG_W + gx);
                float4 v0 = rp[0], v1 = rp[1];
                A[r][0] = v0.x; A[r][1] = v0.y; A[r][2] = v0.z; A[r][3] = v0.w;
                A[r][4] = v1.x; A[r][5] = v1.y; A[r][6] = v1.z; A[r][7] = v1.w;
            }
        } else {
            #pragma unroll
            for (int r = 0; r < RH; ++r) {
                const int yr = gy + r;
                const int yy = min(max(yr, 0), IMG_H - 1);
                float rmv = (yr >= 0 && yr < IMG_H) ? 1.f : 0.f;
                const float* rp = xc + (size_t)yy * IMG_W;
                #pragma unroll
                for (int c = 0; c < RW; ++c) {
                    const int xr = gx + c;
                    const int xx = min(max(xr, 0), IMG_W - 1);
                    float m = rmv;
                    if (XM) m *= colm[c];
                    A[r][c] = rp[xx] * m;
                }
            }
        }
    } else {
        #pragma unroll
        for (int r = 0; r < RH; ++r) {
            const float4* rp = (const float4*)(xc + (size_t)(gy + r) * IMG_W + gx);
            float4 v0 = rp[0], v1 = rp[1];
            A[r][0] = v0.x; A[r][1] = v0.y; A[r][2] = v0.z; A[r][3] = v0.w;
            A[r][4] = v1.x; A[r][5] = v1.y; A[r][6] = v1.z; A[r][7] = v1.w;
        }
    }
    #pragma unroll
    for (int r = 0; r < RH; ++r) {
        #pragma unroll
        for (int c = 0; c < RW; ++c) acc[r][c] = A[r][c];
    }

    // Vertical-neighbor lane addressing: chunk above/below is lane -/+16 within
    // the same wave for 3 of 4 chunk-row boundaries (ty>>4 mapping puts wave w
    // on chunk-rows 4w..4w+3). Wrap garbage lands only in halo rows.
    const int upA = ((lane - 16) & 63) << 2;
    const int dnA = ((lane + 16) & 63) << 2;
    const int gq = ty >> 2;   // slab (wave) id 0..3
    const int tw = ty & 3;    // chunk-row within slab

    #pragma unroll 1
    for (int s = 0; s < NSTEP; ++s) {
        float hc[RW], h7[RW];
        hrow(A[0], hc);
        hrow(A[RH - 1], h7);
        // Intra-wave vertical exchange: pull up-neighbor's h7 and down-neighbor's
        // h0 via bpermute. Issued before the barrier so the barrier drain covers
        // their latency.
        float hm1[RW], hbot[RW];
        #pragma unroll
        for (int c = 0; c < RW; ++c) hm1[c] = bperm(upA, h7[c]);
        #pragma unroll
        for (int c = 0; c < RW; ++c) hbot[c] = bperm(dnA, hc[c]);

        const int buf = s & 1;
        // Cross-wave exchange via tiny LDS (only slab-edge chunk-rows).
        if (tw == 3) {
            botR[buf][gq][tx][0] = make_float4(h7[0], h7[1], h7[2], h7[3]);
            botR[buf][gq][tx][1] = make_float4(h7[4], h7[5], h7[6], h7[7]);
        } else if (tw == 0) {
            topR[buf][gq][tx][0] = make_float4(hc[0], hc[1], hc[2], hc[3]);
            topR[buf][gq][tx][1] = make_float4(hc[4], hc[5], hc[6], hc[7]);
        }
        __syncthreads();
        if (tw == 0) {
            if (gq > 0) {   // slab above exists; ty==0 keeps wrap garbage (halo)
                float4 u0 = botR[buf][gq - 1][tx][0], u1 = botR[buf][gq - 1][tx][1];
                hm1[0] = u0.x; hm1[1] = u0.y; hm1[2] = u0.z; hm1[3] = u0.w;
                hm1[4] = u1.x; hm1[5] = u1.y; hm1[6] = u1.z; hm1[7] = u1.w;
            }
        } else if (tw == 3) {
            if (gq < 3) {   // slab below exists; ty==15 keeps wrap garbage
                float4 d0 = topR[buf][gq + 1][tx][0], d1 = topR[buf][gq + 1][tx][1];
                hbot[0] = d0.x; hbot[1] = d0.y; hbot[2] = d0.z; hbot[3] = d0.w;
                hbot[4] = d1.x; hbot[5] = d1.y; hbot[6] = d1.z; hbot[7] = d1.w;
            }
        }

        // Row 1 first: gives the masked LDS-override reads ~1 row of cover
        // before row 0 consumes hm1. Then rows 2..7 rolling.
        float h1[RW]; hrow(A[1], h1);
        float h2[RW]; hrow(A[2], h2);
        rowop<XM, YM>(hc, h1, h2, A[1], acc[1], colm, YM ? rowm[1] : 1.f, needR);
        rowop<XM, YM>(hm1, hc, h1, A[0], acc[0], colm, YM ? rowm[0] : 1.f, needR);
        float h3[RW]; hrow(A[3], h3);
        rowop<XM, YM>(h1, h2, h3, A[2], acc[2], colm, YM ? rowm[2] : 1.f, needR);
        float h4[RW]; hrow(A[4], h4);
        rowop<XM, YM>(h2, h3, h4, A[3], acc[3], colm, YM ? rowm[3] : 1.f, needR);
        float h5[RW]; hrow(A[5], h5);
        rowop<XM, YM>(h3, h4, h5, A[4], acc[4], colm, YM ? rowm[4] : 1.f, needR);
        float h6[RW]; hrow(A[6], h6);
        rowop<XM, YM>(h4, h5, h6, A[5], acc[5], colm, YM ? rowm[5] : 1.f, needR);
        rowop<XM, YM>(h5, h6, h7, A[6], acc[6], colm, YM ? rowm[6] : 1.f, needR);
        rowop<XM, YM>(h6, h7, hbot, A[7], acc[7], colm, YM ? rowm[7] : 1.f, needR);
    }

    // Epilogue: store central TILE x TILE (region coords [HALO, HALO+TILE))
    if (XM || YM) {
        #pragma unroll
        for (int r = 0; r < RH; ++r) {
            const int rr = ry + r;
            const int yy = gy0 + rr;
            if (rr >= HALO && rr < HALO + TILE && yy < IMG_H) {
                #pragma unroll
                for (int c = 0; c < RW; ++c) {
                    const int cc = rx + c;
                    const int xx = gx0 + cc;
                    if (cc >= HALO && cc < HALO + TILE && xx < IMG_W)
                        oc[(size_t)yy * IMG_W + xx] = 0.05f * acc[r][c];
                }
            }
        }
    } else {
        #pragma unroll
        for (int r = 0; r < RH; ++r) {
            const int rr = ry + r;
            if (rr < HALO || rr >= HALO + TILE) continue;
            const int yy = gy0 + rr;
            float* rowp = oc + (size_t)yy * IMG_W + gx;
            if (tx >= 3 && tx <= 12) {
                ((float4*)rowp)[0] = make_float4(0.05f * acc[r][0], 0.05f * acc[r][1],
                                                 0.05f * acc[r][2], 0.05f * acc[r][3]);
                ((float4*)rowp)[1] = make_float4(0.05f * acc[r][4], 0.05f * acc[r][5],
                                                 0.05f * acc[r][6], 0.05f * acc[r][7]);
            } else if (tx == 2) {        // cols 16..23, valid 20..23 -> c=4..7
                ((float4*)rowp)[1] = make_float4(0.05f * acc[r][4], 0.05f * acc[r][5],
                                                 0.05f * acc[r][6], 0.05f * acc[r][7]);
            } else if (tx == 13) {       // cols 104..111, valid 104..107 -> c=0..3
                ((float4*)rowp)[0] = make_float4(0.05f * acc[r][0], 0.05f * acc[r][1],
                                                 0.05f * acc[r][2], 0.05f * acc[r][3]);
            }
        }
    }
}

__global__ __launch_bounds__(256, 2)
void blur_outwards_kernel(const float* __restrict__ x, float* __restrict__ out) {
    // Cross-wave boundary rows only: 2 bufs x 4 slabs x 16 tx x 32 B = 4 KB each.
    __shared__ float4 botR[2][4][16][2];
    __shared__ float4 topR[2][4][16][2];

    const int tid = threadIdx.x;
    const int tx = tid & 15;
    const int ty = tid >> 4;
    const int lane = tid & 63;

    const int ch  = blockIdx.z;                       // 0..95
    const int gx0 = (int)blockIdx.x * TILE - HALO;
    const int gy0 = (int)blockIdx.y * TILE - HALO;

    const float* __restrict__ xc = x + (size_t)ch * (IMG_W * IMG_H);
    float* __restrict__ oc = out + (size_t)ch * (IMG_W * IMG_H);

    const bool xe = (gx0 < 0) || (gx0 + REG > IMG_W);
    const bool ye = (gy0 < 0) || (gy0 + REG > IMG_H);
    if (!xe && !ye)      body<false, false>(xc, oc, gx0, gy0, tx, ty, lane, botR, topR);
    else if (xe && !ye)  body<true,  false>(xc, oc, gx0, gy0, tx, ty, lane, botR, topR);
    else if (!xe && ye)  body<false, true >(xc, oc, gx0, gy0, tx, ty, lane, botR, topR);
    else                 body<true,  true >(xc, oc, gx0, gy0, tx, ty, lane, botR, topR);
}

extern "C" void kernel_launch(void* const* d_in, const int* in_sizes, int n_in,
                              void* d_out, int out_size, void* d_ws, size_t ws_size,
                              hipStream_t stream) {
    const float* x = (const float*)d_in[0];
    float* out = (float*)d_out;
    dim3 grid((IMG_W + TILE - 1) / TILE,   // 6
              (IMG_H + TILE - 1) / TILE,   // 6
              96);                          // 32 batch * 3 channels
    blur_outwards_kernel<<<grid, 256, 0, stream>>>(x, out);
}